// Round 1
// baseline (597.265 us; speedup 1.0000x reference)
//
#include <hip/hip_runtime.h>

#define HH 96
#define WW 96
#define CC 128
#define C2 256
#define OCOFF 18
#define PLANE (HH*WW)          // 9216

// ---------------- Kernel 1: offset conv (partial sums into d_out ch 0..71) ---------
// grid: 4 (b) * 36 (16x16 tiles) * 4 (c-quarters) = 576 blocks, 256 threads
__global__ __launch_bounds__(256) void offset_conv_kernel(
    const float* __restrict__ lr, const float* __restrict__ hr,
    const float* __restrict__ w_off, float* __restrict__ outp)
{
    __shared__ float tile[18*18];
    const int bid = blockIdx.x;
    const int q   = bid & 3;          // c-quarter
    const int t   = bid >> 2;
    const int b   = t / 36;
    const int rr  = t % 36;
    const int h0  = (rr / 6) * 16;
    const int w0  = (rr % 6) * 16;
    const int tid = threadIdx.x;
    const int py  = tid >> 4;
    const int px  = tid & 15;
    const int h   = h0 + py;
    const int w   = w0 + px;

    float acc[18];
#pragma unroll
    for (int oc = 0; oc < 18; ++oc) acc[oc] = 0.f;

    const int c0 = q * 64;
    for (int c = c0; c < c0 + 64; ++c) {
        const float* plane = (c < CC ? lr : hr) + ((size_t)(b*CC + (c & (CC-1)))) * PLANE;
        __syncthreads();
        for (int j = tid; j < 324; j += 256) {
            int ty2 = j / 18, tx2 = j - ty2*18;
            int gy = h0 - 1 + ty2, gx = w0 - 1 + tx2;
            float v = 0.f;
            if ((unsigned)gy < (unsigned)HH && (unsigned)gx < (unsigned)WW)
                v = plane[gy*WW + gx];
            tile[j] = v;
        }
        __syncthreads();
        float tv[9];
#pragma unroll
        for (int ky = 0; ky < 3; ++ky)
#pragma unroll
            for (int kx = 0; kx < 3; ++kx)
                tv[ky*3+kx] = tile[(py+ky)*18 + (px+kx)];
        const float* wb = w_off + (size_t)c * 9;   // + oc*2304 + tap
#pragma unroll
        for (int oc = 0; oc < 18; ++oc) {
            const float* wp = wb + (size_t)oc * (C2*9);  // uniform -> s_load
#pragma unroll
            for (int tap = 0; tap < 9; ++tap)
                acc[oc] = fmaf(wp[tap], tv[tap], acc[oc]);
        }
    }
    // partial q for out-channel oc stored at d_out channel q*18+oc (overwritten later)
#pragma unroll
    for (int oc = 0; oc < 18; ++oc)
        outp[((size_t)(b*CC + q*18 + oc)) * PLANE + h*WW + w] = acc[oc];
}

// ---------------- Kernel 2: deformable conv ----------------------------------------
// grid: 4 (b) * 96 (h) * 3 (32-px segments) = 1152 blocks, 128 threads
__global__ __launch_bounds__(128) void deform_conv_kernel(
    const float* __restrict__ hr, const float* __restrict__ b_off,
    const float* __restrict__ w_def, const float* __restrict__ b_def,
    float* __restrict__ outp)
{
    __shared__ __align__(16) float samp_lds[32*72];    // [px][r]
    __shared__ __align__(16) float wgt_lds[128*72];    // [oc][r]
    __shared__ short4 gyx[9*32];                        // y0c,y1c,x0c,x1c per (k,px)
    __shared__ __align__(16) float4 gw[9*32];           // masked bilinear weights

    const int bid = blockIdx.x;
    const int tx  = bid % 3;
    const int tmp = bid / 3;
    const int h   = tmp % HH;
    const int b   = tmp / HH;
    const int w0  = tx * 32;
    const int tid = threadIdx.x;

    // ---- Phase A: geometry from offset partials (stored in d_out ch 0..71) ----
    for (int t = tid; t < 9*32; t += 128) {
        int kk = t >> 5;
        int px = t & 31;
        int w  = w0 + px;
        int hw = h*WW + w;
        float offy = b_off[2*kk], offx = b_off[2*kk+1];
#pragma unroll
        for (int q = 0; q < 4; ++q) {
            offy += outp[((size_t)(b*CC + q*18 + 2*kk    )) * PLANE + hw];
            offx += outp[((size_t)(b*CC + q*18 + 2*kk + 1)) * PLANE + hw];
        }
        float sy = (float)h + (float)(kk/3 - 1) + offy;
        float sx = (float)w + (float)(kk%3 - 1) + offx;
        float y0f = floorf(sy), x0f = floorf(sx);
        float dy = sy - y0f,   dx = sx - x0f;
        int y0 = (int)y0f, x0 = (int)x0f;
        int y1 = y0 + 1,   x1 = x0 + 1;
        bool y0v = (unsigned)y0 < (unsigned)HH, y1v = (unsigned)y1 < (unsigned)HH;
        bool x0v = (unsigned)x0 < (unsigned)WW, x1v = (unsigned)x1 < (unsigned)WW;
        float ody = 1.f - dy, odx = 1.f - dx;
        float4 wv;
        wv.x = (y0v && x0v) ? ody*odx : 0.f;
        wv.y = (y0v && x1v) ? ody*dx  : 0.f;
        wv.z = (y1v && x0v) ? dy*odx  : 0.f;
        wv.w = (y1v && x1v) ? dy*dx   : 0.f;
        short4 g;
        g.x = (short)min(max(y0, 0), HH-1);
        g.y = (short)min(max(y1, 0), HH-1);
        g.z = (short)min(max(x0, 0), WW-1);
        g.w = (short)min(max(x1, 0), WW-1);
        gyx[t] = g;
        gw[t]  = wv;
    }

    const int pxq = tid & 7;    // owns px = pxq + 8*j, j=0..3
    const int ocb = tid >> 3;   // owns oc = ocb + 16*i, i=0..7
    float acc[8][4];
#pragma unroll
    for (int i = 0; i < 8; ++i)
#pragma unroll
        for (int j = 0; j < 4; ++j) acc[i][j] = 0.f;

    const float* hrb = hr + (size_t)b * CC * PLANE;

    for (int ic0 = 0; ic0 < CC; ic0 += 8) {
        __syncthreads();   // prev FMA reads done; geometry ready (first iter)
        // build samp tile: 8 ic * 9 k = 72 r  x 32 px
        const float* hrp = hrb + (size_t)ic0 * PLANE;
        for (int t = tid; t < 72*32; t += 128) {
            int r  = t >> 5;
            int px = t & 31;
            int i8 = r / 9;
            int kk = r - i8*9;
            int g  = kk*32 + px;
            short4 yx = gyx[g];
            float4 wv = gw[g];
            const float* hp = hrp + (size_t)i8 * PLANE;
            float v00 = hp[yx.x*WW + yx.z];
            float v01 = hp[yx.x*WW + yx.w];
            float v10 = hp[yx.y*WW + yx.z];
            float v11 = hp[yx.y*WW + yx.w];
            samp_lds[px*72 + r] = fmaf(wv.x, v00, fmaf(wv.y, v01, fmaf(wv.z, v10, wv.w*v11)));
        }
        // stage weight chunk: w_def[oc][ic0..ic0+8][k] -> wgt_lds[oc][r], r contiguous
        {
            const float* wsrc = w_def + (size_t)ic0 * 9;
            for (int j = tid; j < 128*72; j += 128) {
                int oc = j / 72;
                int r  = j - oc*72;
                wgt_lds[j] = wsrc[(size_t)oc * (CC*9) + r];
            }
        }
        __syncthreads();
        // register-tiled FMA: 4 px x 8 oc per thread
        for (int r4 = 0; r4 < 18; ++r4) {
            float4 s[4];
#pragma unroll
            for (int j = 0; j < 4; ++j)
                s[j] = *reinterpret_cast<const float4*>(&samp_lds[(pxq + 8*j)*72 + r4*4]);
#pragma unroll
            for (int i = 0; i < 8; ++i) {
                float4 wv = *reinterpret_cast<const float4*>(&wgt_lds[(ocb + 16*i)*72 + r4*4]);
#pragma unroll
                for (int j = 0; j < 4; ++j) {
                    acc[i][j] = fmaf(wv.x, s[j].x, acc[i][j]);
                    acc[i][j] = fmaf(wv.y, s[j].y, acc[i][j]);
                    acc[i][j] = fmaf(wv.z, s[j].z, acc[i][j]);
                    acc[i][j] = fmaf(wv.w, s[j].w, acc[i][j]);
                }
            }
        }
    }

    // epilogue: add bias, write (overwrites the partial-offset scratch channels too)
#pragma unroll
    for (int i = 0; i < 8; ++i) {
        int oc = ocb + 16*i;
        float bd = b_def[oc];
#pragma unroll
        for (int j = 0; j < 4; ++j) {
            int w = w0 + pxq + 8*j;
            outp[((size_t)(b*CC + oc)) * PLANE + h*WW + w] = acc[i][j] + bd;
        }
    }
}

extern "C" void kernel_launch(void* const* d_in, const int* in_sizes, int n_in,
                              void* d_out, int out_size, void* d_ws, size_t ws_size,
                              hipStream_t stream)
{
    const float* lr    = (const float*)d_in[0];
    const float* hr    = (const float*)d_in[1];
    const float* w_off = (const float*)d_in[2];
    const float* b_off = (const float*)d_in[3];
    const float* w_def = (const float*)d_in[4];
    const float* b_def = (const float*)d_in[5];
    float* outp = (float*)d_out;

    offset_conv_kernel<<<576, 256, 0, stream>>>(lr, hr, w_off, outp);
    deform_conv_kernel<<<1152, 128, 0, stream>>>(hr, b_off, w_def, b_def, outp);
}

// Round 2
// 374.975 us; speedup vs baseline: 1.5928x; 1.5928x over previous
//
#include <hip/hip_runtime.h>
#include <hip/hip_bf16.h>

#define HH 96
#define WW 96
#define CC 128
#define C2 256
#define PLANE (HH*WW)          // 9216
#define KTOT 1152              // 128 ic * 9 taps
#define CK 64                  // k per chunk
#define NCHUNK (KTOT/CK)       // 18
#define PXT 64                 // pixels per block (flattened hw)

typedef __attribute__((ext_vector_type(8))) short bf16x8;
typedef __attribute__((ext_vector_type(4))) float f32x4;

// XOR-swizzle within a 128B row: byte bits 4..6 ^= (row&7)
__device__ __forceinline__ int swz(int row, int byte_in_row) {
    return row * 128 + (byte_in_row ^ ((row & 7) << 4));
}

// ---------------- Kernel 0: convert w_def fp32 -> bf16 in d_ws ---------------------
__global__ __launch_bounds__(256) void wcvt_kernel(const float* __restrict__ w,
                                                   unsigned short* __restrict__ o)
{
    int i = blockIdx.x * 256 + threadIdx.x;   // grid covers 147456
    if (i < CC * KTOT)
        o[i] = __bfloat16_as_ushort(__float2bfloat16(w[i]));
}

// ---------------- Kernel 1: offset conv (partial sums into d_out ch 0..71) ---------
// grid: 4 (b) * 36 (16x16 tiles) * 4 (c-quarters) = 576 blocks, 256 threads
__global__ __launch_bounds__(256) void offset_conv_kernel(
    const float* __restrict__ lr, const float* __restrict__ hr,
    const float* __restrict__ w_off, float* __restrict__ outp)
{
    __shared__ float tile[18*18];
    const int bid = blockIdx.x;
    const int q   = bid & 3;          // c-quarter
    const int t   = bid >> 2;
    const int b   = t / 36;
    const int rr  = t % 36;
    const int h0  = (rr / 6) * 16;
    const int w0  = (rr % 6) * 16;
    const int tid = threadIdx.x;
    const int py  = tid >> 4;
    const int px  = tid & 15;
    const int h   = h0 + py;
    const int w   = w0 + px;

    float acc[18];
#pragma unroll
    for (int oc = 0; oc < 18; ++oc) acc[oc] = 0.f;

    const int c0 = q * 64;
    for (int c = c0; c < c0 + 64; ++c) {
        const float* plane = (c < CC ? lr : hr) + ((size_t)(b*CC + (c & (CC-1)))) * PLANE;
        __syncthreads();
        for (int j = tid; j < 324; j += 256) {
            int ty2 = j / 18, tx2 = j - ty2*18;
            int gy = h0 - 1 + ty2, gx = w0 - 1 + tx2;
            float v = 0.f;
            if ((unsigned)gy < (unsigned)HH && (unsigned)gx < (unsigned)WW)
                v = plane[gy*WW + gx];
            tile[j] = v;
        }
        __syncthreads();
        float tv[9];
#pragma unroll
        for (int ky = 0; ky < 3; ++ky)
#pragma unroll
            for (int kx = 0; kx < 3; ++kx)
                tv[ky*3+kx] = tile[(py+ky)*18 + (px+kx)];
        const float* wb = w_off + (size_t)c * 9;
#pragma unroll
        for (int oc = 0; oc < 18; ++oc) {
            const float* wp = wb + (size_t)oc * (C2*9);  // uniform -> s_load
#pragma unroll
            for (int tap = 0; tap < 9; ++tap)
                acc[oc] = fmaf(wp[tap], tv[tap], acc[oc]);
        }
    }
#pragma unroll
    for (int oc = 0; oc < 18; ++oc)
        outp[((size_t)(b*CC + q*18 + oc)) * PLANE + h*WW + w] = acc[oc];
}

// ---------------- Kernel 2: deformable conv as bf16 MFMA gather-GEMM ---------------
// grid: 4 (b) * 144 (64-px segments) = 576 blocks, 256 threads (4 waves)
// out tile: 128 oc x 64 px; K = 1152 in 18 chunks of 64
__global__ __launch_bounds__(256) void deform_mfma_kernel(
    const float* __restrict__ hr, const float* __restrict__ b_off,
    const unsigned short* __restrict__ wbf, const float* __restrict__ b_def,
    float* __restrict__ outp)
{
    __shared__ __align__(16) unsigned short wgt_lds[CC * CK];    // swizzled [oc][k], 16KB
    __shared__ __align__(16) unsigned short samp_lds[PXT * CK];  // swizzled [px][k], 8KB
    __shared__ short4 gyx[9 * PXT];                              // clamped y0,y1,x0,x1
    __shared__ float gw0[9*PXT], gw1[9*PXT], gw2[9*PXT], gw3[9*PXT]; // masked bilinear wts
    __shared__ float bias_lds[CC];

    const int bid = blockIdx.x;
    const int b   = bid / (PLANE / PXT);    // /144
    const int seg = bid % (PLANE / PXT);
    const int hw0 = seg * PXT;
    const int tid = threadIdx.x;

    // ---- Phase A: geometry from offset partials (d_out ch 0..71) ----
    for (int t = tid; t < 9 * PXT; t += 256) {
        int kk = t >> 6;           // tap
        int px = t & (PXT - 1);
        int hw = hw0 + px;
        int h = hw / WW, w = hw - h * WW;
        float offy = b_off[2*kk], offx = b_off[2*kk + 1];
#pragma unroll
        for (int q = 0; q < 4; ++q) {
            offy += outp[((size_t)(b*CC + q*18 + 2*kk    )) * PLANE + hw];
            offx += outp[((size_t)(b*CC + q*18 + 2*kk + 1)) * PLANE + hw];
        }
        float sy = (float)h + (float)(kk/3 - 1) + offy;
        float sx = (float)w + (float)(kk%3 - 1) + offx;
        float y0f = floorf(sy), x0f = floorf(sx);
        float dy = sy - y0f,   dx = sx - x0f;
        int y0 = (int)y0f, x0 = (int)x0f;
        int y1 = y0 + 1,   x1 = x0 + 1;
        bool y0v = (unsigned)y0 < (unsigned)HH, y1v = (unsigned)y1 < (unsigned)HH;
        bool x0v = (unsigned)x0 < (unsigned)WW, x1v = (unsigned)x1 < (unsigned)WW;
        float ody = 1.f - dy, odx = 1.f - dx;
        gw0[t] = (y0v && x0v) ? ody*odx : 0.f;
        gw1[t] = (y0v && x1v) ? ody*dx  : 0.f;
        gw2[t] = (y1v && x0v) ? dy*odx  : 0.f;
        gw3[t] = (y1v && x1v) ? dy*dx   : 0.f;
        short4 g;
        g.x = (short)min(max(y0, 0), HH-1);
        g.y = (short)min(max(y1, 0), HH-1);
        g.z = (short)min(max(x0, 0), WW-1);
        g.w = (short)min(max(x1, 0), WW-1);
        gyx[t] = g;
    }
    if (tid < CC) bias_lds[tid] = b_def[tid];

    const int px  = tid & 63;
    const int rq  = tid >> 6;        // 0..3
    const int lane = tid & 63;
    const int wid  = tid >> 6;       // wave id 0..3
    const int oc0  = wid * 32;
    const int l15  = lane & 15;
    const int l4   = lane >> 4;

    f32x4 acc[2][4];
#pragma unroll
    for (int mf = 0; mf < 2; ++mf)
#pragma unroll
        for (int nf = 0; nf < 4; ++nf)
            acc[mf][nf] = (f32x4){0.f, 0.f, 0.f, 0.f};

    const float* hrb = hr + (size_t)b * CC * PLANE;

    for (int ch = 0; ch < NCHUNK; ++ch) {
        const int k0 = ch * CK;
        __syncthreads();   // prev MFMA reads done; geometry ready (first iter)

        // ---- stage weight chunk: [oc][64k] bf16, swizzled ----
        {
            int oc = tid >> 1;
            int kh = (tid & 1) * 32;
            const unsigned short* src = wbf + (size_t)oc * KTOT + k0 + kh;
#pragma unroll
            for (int j = 0; j < 4; ++j) {
                bf16x8 v = *reinterpret_cast<const bf16x8*>(src + j*8);
                *reinterpret_cast<bf16x8*>((char*)wgt_lds + swz(oc, (kh + j*8)*2)) = v;
            }
        }
        // ---- build samp chunk: [px][64k] bf16, swizzled; 2 k per iter ----
#pragma unroll
        for (int it = 0; it < 8; ++it) {
            int r = rq*2 + it*8;     // even r in 0..62
            unsigned out2 = 0;
#pragma unroll
            for (int s = 0; s < 2; ++s) {
                int k  = k0 + r + s;
                int ic = k / 9;
                int tap = k - ic*9;
                int g  = tap * PXT + px;
                short4 yx = gyx[g];
                const float* hp = hrb + (size_t)ic * PLANE;
                float v00 = hp[yx.x*WW + yx.z];
                float v01 = hp[yx.x*WW + yx.w];
                float v10 = hp[yx.y*WW + yx.z];
                float v11 = hp[yx.y*WW + yx.w];
                float sv = fmaf(gw0[g], v00, fmaf(gw1[g], v01,
                           fmaf(gw2[g], v10, gw3[g]*v11)));
                unsigned short us = __bfloat16_as_ushort(__float2bfloat16(sv));
                out2 |= (unsigned)us << (16*s);
            }
            *reinterpret_cast<unsigned*>((char*)samp_lds + swz(px, r*2)) = out2;
        }
        __syncthreads();

        // ---- MFMA: 2 k-steps of 32 ----
#pragma unroll
        for (int ks = 0; ks < 2; ++ks) {
            int kb = (ks*32 + l4*8) * 2;    // byte offset in row
            bf16x8 afr[2], bfr[4];
#pragma unroll
            for (int mf = 0; mf < 2; ++mf) {
                int oc = oc0 + mf*16 + l15;
                afr[mf] = *reinterpret_cast<const bf16x8*>((char*)wgt_lds + swz(oc, kb));
            }
#pragma unroll
            for (int nf = 0; nf < 4; ++nf) {
                int p = nf*16 + l15;
                bfr[nf] = *reinterpret_cast<const bf16x8*>((char*)samp_lds + swz(p, kb));
            }
#pragma unroll
            for (int mf = 0; mf < 2; ++mf)
#pragma unroll
                for (int nf = 0; nf < 4; ++nf)
                    acc[mf][nf] = __builtin_amdgcn_mfma_f32_16x16x32_bf16(
                        afr[mf], bfr[nf], acc[mf][nf], 0, 0, 0);
        }
    }

    // ---- epilogue: bias + store (D: row=oc=(l>>4)*4+reg, col=px=l&15) ----
#pragma unroll
    for (int mf = 0; mf < 2; ++mf) {
#pragma unroll
        for (int r = 0; r < 4; ++r) {
            int oc = oc0 + mf*16 + l4*4 + r;
            float bd = bias_lds[oc];
#pragma unroll
            for (int nf = 0; nf < 4; ++nf) {
                int p = nf*16 + l15;
                outp[((size_t)(b*CC + oc)) * PLANE + hw0 + p] = acc[mf][nf][r] + bd;
            }
        }
    }
}

extern "C" void kernel_launch(void* const* d_in, const int* in_sizes, int n_in,
                              void* d_out, int out_size, void* d_ws, size_t ws_size,
                              hipStream_t stream)
{
    const float* lr    = (const float*)d_in[0];
    const float* hr    = (const float*)d_in[1];
    const float* w_off = (const float*)d_in[2];
    const float* b_off = (const float*)d_in[3];
    const float* w_def = (const float*)d_in[4];
    const float* b_def = (const float*)d_in[5];
    float* outp = (float*)d_out;
    unsigned short* wbf = (unsigned short*)d_ws;   // 147456 * 2B = 288KB

    wcvt_kernel<<<(CC*KTOT + 255)/256, 256, 0, stream>>>(w_def, wbf);
    offset_conv_kernel<<<576, 256, 0, stream>>>(lr, hr, w_off, outp);
    deform_mfma_kernel<<<576, 256, 0, stream>>>(hr, b_off, wbf, b_def, outp);
}

// Round 3
// 284.670 us; speedup vs baseline: 2.0981x; 1.3172x over previous
//
#include <hip/hip_runtime.h>
#include <hip/hip_bf16.h>

#define HH 96
#define WW 96
#define CC 128
#define C2 256
#define PLANE (HH*WW)          // 9216
#define KTOT 1152              // 9 taps * 128 ic, ordered [tap][ic]
#define PXT 64                 // pixels per K2 block
#define NSEG (PLANE/PXT)       // 144
#define NGRP 6                 // K1 channel groups (partials in d_out ch 0..107)

typedef __attribute__((ext_vector_type(8))) short bf16x8;
typedef __attribute__((ext_vector_type(4))) float f32x4;
typedef __attribute__((ext_vector_type(4))) unsigned int u32x4;

// XOR-swizzle within a 128B row: byte bits 4..6 ^= (row&7)
__device__ __forceinline__ int swz(int row, int byte_in_row) {
    return row * 128 + (byte_in_row ^ ((row & 7) << 4));
}

// ---------------- Kernel 0: w_def fp32 -> bf16, reordered to [oc][tap][ic] --------
__global__ __launch_bounds__(256) void wcvt_kernel(const float* __restrict__ w,
                                                   unsigned short* __restrict__ o)
{
    int i = blockIdx.x * 256 + threadIdx.x;
    if (i < CC * KTOT) {
        int oc = i / KTOT;
        int r  = i - oc * KTOT;
        int tap = r >> 7;
        int ic  = r & 127;
        o[i] = __bfloat16_as_ushort(__float2bfloat16(w[(size_t)(oc*CC + ic)*9 + tap]));
    }
}

// ---------------- Kernel 1: offset conv (partials into d_out ch 0..107) ------------
// grid: 4 (b) * 36 (16x16 tiles) * 6 (c-groups) = 864 blocks, 256 threads
__global__ __launch_bounds__(256) void offset_conv_kernel(
    const float* __restrict__ lr, const float* __restrict__ hr,
    const float* __restrict__ w_off, float* __restrict__ outp)
{
    __shared__ float tile[2][324];
    const int bid = blockIdx.x;
    const int q   = bid % NGRP;
    const int t   = bid / NGRP;
    const int b   = t / 36;
    const int rr  = t % 36;
    const int h0  = (rr / 6) * 16;
    const int w0  = (rr % 6) * 16;
    const int tid = threadIdx.x;
    const int py  = tid >> 4;
    const int px  = tid & 15;

    const int c0 = (C2 * q) / NGRP, c1 = (C2 * (q + 1)) / NGRP;
    const float* srcp = (q < 3) ? lr : hr;   // group boundaries align with 128
    const int cofs = (q < 3) ? 0 : CC;

    // staging geometry for this thread's 1-2 halo elements
    int gy0 = h0 - 1 + tid / 18, gx0 = w0 - 1 + tid % 18;
    bool ok0 = (unsigned)gy0 < (unsigned)HH && (unsigned)gx0 < (unsigned)WW;
    int off0 = gy0 * WW + gx0;
    int j1 = tid + 256;
    int gy1 = h0 - 1 + j1 / 18, gx1 = w0 - 1 + j1 % 18;
    bool ok1 = (j1 < 324) && (unsigned)gy1 < (unsigned)HH && (unsigned)gx1 < (unsigned)WW;
    int off1 = gy1 * WW + gx1;

    float acc[18];
#pragma unroll
    for (int oc = 0; oc < 18; ++oc) acc[oc] = 0.f;

    const float* pl = srcp + (size_t)(b * CC + c0 - cofs) * PLANE;
    float p0 = ok0 ? pl[off0] : 0.f;
    float p1 = ok1 ? pl[off1] : 0.f;

    for (int c = c0; c < c1; ++c) {
        float* tb = tile[c & 1];
        tb[tid] = p0;
        if (j1 < 324) tb[j1] = p1;
        __syncthreads();
        if (c + 1 < c1) {
            const float* pn = srcp + (size_t)(b * CC + c + 1 - cofs) * PLANE;
            p0 = ok0 ? pn[off0] : 0.f;
            p1 = ok1 ? pn[off1] : 0.f;
        }
        float tv[9];
#pragma unroll
        for (int ky = 0; ky < 3; ++ky)
#pragma unroll
            for (int kx = 0; kx < 3; ++kx)
                tv[ky*3+kx] = tb[(py+ky)*18 + px + kx];
#pragma unroll
        for (int oc = 0; oc < 18; ++oc) {
            const float* wp = w_off + (size_t)(oc * C2 + c) * 9;   // uniform -> s_load
#pragma unroll
            for (int tap = 0; tap < 9; ++tap)
                acc[oc] = fmaf(wp[tap], tv[tap], acc[oc]);
        }
    }
#pragma unroll
    for (int oc = 0; oc < 18; ++oc)
        outp[((size_t)(b*CC + q*18 + oc)) * PLANE + (h0+py)*WW + (w0+px)] = acc[oc];
}

// ---------------- Kernel 2: deformable conv, bf16 MFMA, [tap][ic] K-order ----------
// grid: 4 (b) * 144 segs = 576 blocks, 512 threads (8 waves, 16 oc each)
__global__ __launch_bounds__(512, 4) void deform_mfma_kernel(
    const float* __restrict__ hr, const float* __restrict__ b_off,
    const unsigned short* __restrict__ wbf, const float* __restrict__ b_def,
    float* __restrict__ outp)
{
    __shared__ __align__(16) unsigned short wgt_lds[CC * 64];    // 16KB swizzled
    __shared__ __align__(16) unsigned short samp_lds[PXT * 64];  // 8KB swizzled
    __shared__ short4 gyx[9 * PXT];
    __shared__ float gw0[9*PXT], gw1[9*PXT], gw2[9*PXT], gw3[9*PXT];
    __shared__ float bias_lds[CC];

    const int bid = blockIdx.x;
    const int b   = bid / NSEG;
    const int seg = bid % NSEG;
    const int hw0 = seg * PXT;
    const int tid = threadIdx.x;

    // ---- Phase A: geometry from offset partials (d_out ch 0..107) ----
    for (int t = tid; t < 9 * PXT; t += 512) {
        int kk = t >> 6;
        int p2 = t & 63;
        int hw = hw0 + p2;
        int h2 = hw / WW, w2 = hw - h2 * WW;
        float offy = b_off[2*kk], offx = b_off[2*kk + 1];
#pragma unroll
        for (int q = 0; q < NGRP; ++q) {
            offy += outp[((size_t)(b*CC + q*18 + 2*kk    )) * PLANE + hw];
            offx += outp[((size_t)(b*CC + q*18 + 2*kk + 1)) * PLANE + hw];
        }
        float sy = (float)h2 + (float)(kk/3 - 1) + offy;
        float sx = (float)w2 + (float)(kk%3 - 1) + offx;
        float y0f = floorf(sy), x0f = floorf(sx);
        float dy = sy - y0f,   dx = sx - x0f;
        int y0 = (int)y0f, x0 = (int)x0f;
        int y1 = y0 + 1,   x1 = x0 + 1;
        bool y0v = (unsigned)y0 < (unsigned)HH, y1v = (unsigned)y1 < (unsigned)HH;
        bool x0v = (unsigned)x0 < (unsigned)WW, x1v = (unsigned)x1 < (unsigned)WW;
        float ody = 1.f - dy, odx = 1.f - dx;
        gw0[t] = (y0v && x0v) ? ody*odx : 0.f;
        gw1[t] = (y0v && x1v) ? ody*dx  : 0.f;
        gw2[t] = (y1v && x0v) ? dy*odx  : 0.f;
        gw3[t] = (y1v && x1v) ? dy*dx   : 0.f;
        short4 g;
        g.x = (short)min(max(y0, 0), HH-1);
        g.y = (short)min(max(y1, 0), HH-1);
        g.z = (short)min(max(x0, 0), WW-1);
        g.w = (short)min(max(x1, 0), WW-1);
        gyx[t] = g;
    }
    if (tid < CC) bias_lds[tid] = b_def[tid];
    __syncthreads();

    const int px   = tid & 63;
    const int icq  = tid >> 6;       // 0..7 (== wave id)
    const int lane = tid & 63;
    const int oc0  = (tid >> 6) * 16;
    const int l15  = lane & 15;
    const int l4   = lane >> 4;

    f32x4 acc[4];
#pragma unroll
    for (int nf = 0; nf < 4; ++nf) acc[nf] = (f32x4){0.f, 0.f, 0.f, 0.f};

    const float* hrb = hr + (size_t)b * CC * PLANE;

    int o00, o01, o10, o11;
    float g0, g1, g2, g3;
    unsigned sp[4];
    u32x4 wpre[2];

#define GEOM_LOAD(TAP) { \
    int gg = (TAP)*PXT + px; \
    short4 yx = gyx[gg]; \
    o00 = yx.x*WW + yx.z; o01 = yx.x*WW + yx.w; \
    o10 = yx.y*WW + yx.z; o11 = yx.y*WW + yx.w; \
    g0 = gw0[gg]; g1 = gw1[gg]; g2 = gw2[gg]; g3 = gw3[gg]; }

#define GATHER(IC0) { \
    const float* hp = hrb + (size_t)((IC0) + icq*8) * PLANE; \
    float sv[8]; \
    _Pragma("unroll") \
    for (int i = 0; i < 8; ++i) { \
        const float* p = hp + (size_t)i * PLANE; \
        float v00 = p[o00], v01 = p[o01], v10 = p[o10], v11 = p[o11]; \
        sv[i] = fmaf(g0, v00, fmaf(g1, v01, fmaf(g2, v10, g3*v11))); \
    } \
    _Pragma("unroll") \
    for (int j = 0; j < 4; ++j) { \
        unsigned lo = (unsigned)__bfloat16_as_ushort(__float2bfloat16(sv[2*j])); \
        unsigned hi = (unsigned)__bfloat16_as_ushort(__float2bfloat16(sv[2*j+1])); \
        sp[j] = lo | (hi << 16); \
    } }

#define WLOAD(TAP, IC0) { \
    _Pragma("unroll") \
    for (int j2 = 0; j2 < 2; ++j2) { \
        int t2 = tid + j2*512; \
        int oc = t2 >> 3; int slot = t2 & 7; \
        wpre[j2] = *reinterpret_cast<const u32x4*>(wbf + (size_t)oc*KTOT + (TAP)*128 + (IC0) + slot*8); \
    } }

    // prologue: prefetch chunk 0
    GEOM_LOAD(0);
    GATHER(0);
    WLOAD(0, 0);

    for (int ch = 0; ch < 18; ++ch) {
        __syncthreads();   // prev MFMA reads done
        // write staged chunk ch
#pragma unroll
        for (int j2 = 0; j2 < 2; ++j2) {
            int t2 = tid + j2*512;
            int oc = t2 >> 3; int slot = t2 & 7;
            *reinterpret_cast<u32x4*>((char*)wgt_lds + swz(oc, slot*16)) = wpre[j2];
        }
        {
            u32x4 spv = {sp[0], sp[1], sp[2], sp[3]};
            *reinterpret_cast<u32x4*>((char*)samp_lds + swz(px, icq*16)) = spv;
        }
        __syncthreads();
        // prefetch chunk ch+1 (overlaps with MFMA below)
        if (ch < 17) {
            int nc = ch + 1;
            int ntap = nc >> 1;
            int nic0 = (nc & 1) * 64;
            if ((nc & 1) == 0) GEOM_LOAD(ntap);
            GATHER(nic0);
            WLOAD(ntap, nic0);
        }
        // MFMA on chunk ch
#pragma unroll
        for (int ks = 0; ks < 2; ++ks) {
            int kb = ks*64 + l4*16;
            bf16x8 afr = *reinterpret_cast<const bf16x8*>((char*)wgt_lds + swz(oc0 + l15, kb));
#pragma unroll
            for (int nf = 0; nf < 4; ++nf) {
                bf16x8 bfr = *reinterpret_cast<const bf16x8*>((char*)samp_lds + swz(nf*16 + l15, kb));
                acc[nf] = __builtin_amdgcn_mfma_f32_16x16x32_bf16(afr, bfr, acc[nf], 0, 0, 0);
            }
        }
    }

    // ---- epilogue: bias + store ----
#pragma unroll
    for (int r = 0; r < 4; ++r) {
        int oc = oc0 + l4*4 + r;
        float bd = bias_lds[oc];
#pragma unroll
        for (int nf = 0; nf < 4; ++nf)
            outp[((size_t)(b*CC + oc)) * PLANE + hw0 + nf*16 + l15] = acc[nf][r] + bd;
    }
#undef GEOM_LOAD
#undef GATHER
#undef WLOAD
}

extern "C" void kernel_launch(void* const* d_in, const int* in_sizes, int n_in,
                              void* d_out, int out_size, void* d_ws, size_t ws_size,
                              hipStream_t stream)
{
    const float* lr    = (const float*)d_in[0];
    const float* hr    = (const float*)d_in[1];
    const float* w_off = (const float*)d_in[2];
    const float* b_off = (const float*)d_in[3];
    const float* w_def = (const float*)d_in[4];
    const float* b_def = (const float*)d_in[5];
    float* outp = (float*)d_out;
    unsigned short* wbf = (unsigned short*)d_ws;   // 288KB

    wcvt_kernel<<<(CC*KTOT + 255)/256, 256, 0, stream>>>(w_def, wbf);
    offset_conv_kernel<<<4*36*NGRP, 256, 0, stream>>>(lr, hr, w_off, outp);
    deform_mfma_kernel<<<4*NSEG, 512, 0, stream>>>(hr, b_off, wbf, b_def, outp);
}